// Round 4
// baseline (412.170 us; speedup 1.0000x reference)
//
#include <hip/hip_runtime.h>
#include <hip/hip_bf16.h>

#define NPIX 3136
#define BB 4

typedef unsigned short u16;
typedef __bf16 bf16x8 __attribute__((ext_vector_type(8)));
typedef float f32x4 __attribute__((ext_vector_type(4)));

__device__ __forceinline__ float b2f(u16 u) {
  union { unsigned u; float f; } c; c.u = ((unsigned)u) << 16; return c.f;
}
__device__ __forceinline__ u16 f2b(float f) {
  __hip_bfloat16 h = __float2bfloat16(f);
  return *reinterpret_cast<u16*>(&h);
}
__device__ __forceinline__ unsigned pk2(float a, float b) {
  return (unsigned)f2b(a) | ((unsigned)f2b(b) << 16);
}
__device__ __forceinline__ void unpack4(unsigned lo, unsigned hi, float* o) {
  union { unsigned u; float f; } c;
  c.u = lo << 16;          o[0] = c.f;
  c.u = lo & 0xffff0000u;  o[1] = c.f;
  c.u = hi << 16;          o[2] = c.f;
  c.u = hi & 0xffff0000u;  o[3] = c.f;
}

// ---------------------------------------------------------------------------
// 64(o) x 64(n) register-tiled vector GEMM over K channels.
// Input source is either fp32 global (SRC_F32) or bf16 workspace; weights are
// always fp32 global (64 rows, row-major stride K). Both staged into bf16 LDS
// in chunks of <=128 channels (LDS 16KB+16KB). acc is fp32.
// ---------------------------------------------------------------------------
template<int K, bool SRC_F32>
__device__ __forceinline__ void gemm_core(const void* __restrict__ inb_, int n0,
                                          const float* __restrict__ w,
                                          float acc[4][4], u16* sIn, u16* sW) {
  constexpr int KC = (K < 128) ? K : 128;
  const int tid = threadIdx.x;
  const int to = (tid >> 4) * 4;
  const int tn = (tid & 15) * 4;
  for (int k0 = 0; k0 < K; k0 += KC) {
    if (k0) __syncthreads();
    // stage input chunk [c][64 n] as bf16
    if (SRC_F32) {
      const float* inb = (const float*)inb_;
      for (int i = tid; i < KC * 16; i += 256) {
        int c = i >> 4, off = (i & 15) * 4;
        float4 v = *(const float4*)(inb + (size_t)(k0 + c) * NPIX + n0 + off);
        uint2 p; p.x = pk2(v.x, v.y); p.y = pk2(v.z, v.w);
        *(uint2*)(sIn + c * 64 + off) = p;
      }
    } else {
      const u16* inb = (const u16*)inb_;
      for (int i = tid; i < KC * 8; i += 256) {
        int c = i >> 3, off = (i & 7) * 8;
        *(uint4*)(sIn + c * 64 + off) =
            *(const uint4*)(inb + (size_t)(k0 + c) * NPIX + n0 + off);
      }
    }
    // stage weight chunk transposed [c][64 o] as bf16
    for (int i = tid; i < KC * 16; i += 256) {
      int o = i & 63, c0 = (i >> 6) * 4;
      float4 v = *(const float4*)(w + (size_t)o * K + k0 + c0);
      sW[(c0 + 0) * 64 + o] = f2b(v.x);
      sW[(c0 + 1) * 64 + o] = f2b(v.y);
      sW[(c0 + 2) * 64 + o] = f2b(v.z);
      sW[(c0 + 3) * 64 + o] = f2b(v.w);
    }
    __syncthreads();
#pragma unroll 4
    for (int c = 0; c < KC; ++c) {
      uint2 ux = *(const uint2*)(sIn + c * 64 + tn);
      uint2 uw = *(const uint2*)(sW + c * 64 + to);
      float xv[4], wv[4];
      unpack4(ux.x, ux.y, xv);
      unpack4(uw.x, uw.y, wv);
#pragma unroll
      for (int i = 0; i < 4; ++i)
#pragma unroll
        for (int j = 0; j < 4; ++j)
          acc[i][j] += wv[i] * xv[j];
    }
  }
}

// ---------------------------------------------------------------------------
// Kernel 1: fused g/theta/phi 1x1 conv projections (fp32 in -> bf16 ws).
//  g     -> gx (B,128,NPIX)      (natural layout == V^T per group)
//  theta -> Tq (B*G, NPIX, 32)
//  phi   -> Pk (B*G, NPIX, 32)
// ---------------------------------------------------------------------------
__global__ __launch_bounds__(256) void proj_kernel(
    const float* __restrict__ x,
    const float* __restrict__ gw, const float* __restrict__ gb,
    const float* __restrict__ tw, const float* __restrict__ tb,
    const float* __restrict__ pw, const float* __restrict__ pb,
    u16* __restrict__ gx, u16* __restrict__ Tq, u16* __restrict__ Pk) {
  __shared__ __align__(16) u16 sIn[128 * 64];
  __shared__ __align__(16) u16 sW[128 * 64];
  const int b = blockIdx.z, oc = blockIdx.y, nc = blockIdx.x;
  const int obase = oc * 64;
  const int proj = obase >> 7;         // 0:g 1:theta 2:phi
  const int rbase = obase & 127;
  const float* wsel = proj == 0 ? gw : (proj == 1 ? tw : pw);
  const float* bsel = proj == 0 ? gb : (proj == 1 ? tb : pb);
  float acc[4][4] = {};
  gemm_core<256, true>(x + (size_t)b * 256 * NPIX, nc * 64,
                       wsel + (size_t)rbase * 256, acc, sIn, sW);
  const int to = (threadIdx.x >> 4) * 4;
  const int tn = (threadIdx.x & 15) * 4;
  const int n0 = nc * 64 + tn;
  float bv[4];
#pragma unroll
  for (int i = 0; i < 4; ++i) bv[i] = bsel[rbase + to + i];
  if (proj == 0) {
#pragma unroll
    for (int i = 0; i < 4; ++i) {
      int row = rbase + to + i;
      uint2 s;
      s.x = pk2(acc[i][0] + bv[i], acc[i][1] + bv[i]);
      s.y = pk2(acc[i][2] + bv[i], acc[i][3] + bv[i]);
      *(uint2*)(gx + ((size_t)b * 128 + row) * NPIX + n0) = s;
    }
  } else {
    u16* dst = proj == 1 ? Tq : Pk;
    int row0 = rbase + to;
    int gidx = row0 >> 5, d0 = row0 & 31;
    size_t base = (size_t)(b * 4 + gidx) * NPIX * 32;
#pragma unroll
    for (int j = 0; j < 4; ++j) {
      uint2 s;
      s.x = pk2(acc[0][j] + bv[0], acc[1][j] + bv[1]);
      s.y = pk2(acc[2][j] + bv[2], acc[3][j] + bv[3]);
      *(uint2*)(dst + base + (size_t)(n0 + j) * 32 + d0) = s;
    }
  }
}

// ---------------------------------------------------------------------------
// Kernel 2: MFMA flash attention per (b,g). All operands bf16 workspace.
// Q=theta (N,32), K=phi (N,32), V^T = gx rows (32,N).
// No online max (scores bounded, clamp 60 for insurance); row sums via an
// extra MFMA against an all-ones B fragment. Wave owns 32 query rows.
// ---------------------------------------------------------------------------
__global__ __launch_bounds__(256) void attn_kernel(
    const u16* __restrict__ Tq, const u16* __restrict__ Pk,
    const u16* __restrict__ gx, u16* __restrict__ y) {
  __shared__ __align__(16) u16 Plds[4][32][40];   // per-wave P tile, padded rows
  const int bid = blockIdx.x;
  const int bg = bid / 25, qblk = bid % 25;
  const int b = bg >> 2, g = bg & 3;
  const int wave = threadIdx.x >> 6, lane = threadIdx.x & 63;
  const int lr = lane & 15, lq = lane >> 4;
  const int qbase = qblk * 128 + wave * 32;
  const u16* Qp = Tq + (size_t)bg * NPIX * 32;
  const u16* Kp = Pk + (size_t)bg * NPIX * 32;
  const u16* Vp = gx + ((size_t)b * 128 + g * 32) * NPIX;

  bf16x8 qf[2];
#pragma unroll
  for (int qi = 0; qi < 2; ++qi) {
    int row = qbase + qi * 16 + lr;
    row = row < NPIX ? row : NPIX - 1;          // clamp tail (stores guarded)
    qf[qi] = *(const bf16x8*)(Qp + (size_t)row * 32 + lq * 8);
  }
  const f32x4 z4 = {0.f, 0.f, 0.f, 0.f};
  f32x4 O[2][2], Lf[2];
#pragma unroll
  for (int qi = 0; qi < 2; ++qi) {
    O[qi][0] = z4; O[qi][1] = z4; Lf[qi] = z4;
  }
  bf16x8 onef;
#pragma unroll
  for (int j = 0; j < 8; ++j) onef[j] = (__bf16)1.0f;

  for (int kc = 0; kc < NPIX; kc += 32) {
    bf16x8 kf0 = *(const bf16x8*)(Kp + (size_t)(kc + lr) * 32 + lq * 8);
    bf16x8 kf1 = *(const bf16x8*)(Kp + (size_t)(kc + 16 + lr) * 32 + lq * 8);
    f32x4 S[2][2];
    S[0][0] = __builtin_amdgcn_mfma_f32_16x16x32_bf16(qf[0], kf0, z4, 0, 0, 0);
    S[0][1] = __builtin_amdgcn_mfma_f32_16x16x32_bf16(qf[0], kf1, z4, 0, 0, 0);
    S[1][0] = __builtin_amdgcn_mfma_f32_16x16x32_bf16(qf[1], kf0, z4, 0, 0, 0);
    S[1][1] = __builtin_amdgcn_mfma_f32_16x16x32_bf16(qf[1], kf1, z4, 0, 0, 0);
    // p = exp(s); write to LDS in C-layout position (row=lq*4+r, col=lr+16*kt)
#pragma unroll
    for (int qi = 0; qi < 2; ++qi)
#pragma unroll
      for (int kt = 0; kt < 2; ++kt)
#pragma unroll
        for (int r = 0; r < 4; ++r) {
          float p = __expf(fminf(S[qi][kt][r], 60.f));
          Plds[wave][qi * 16 + lq * 4 + r][kt * 16 + lr] = f2b(p);
        }
    // read P back in A-operand layout (row=lr, k=lq*8+j); per-wave buffer,
    // same-wave DS ops are processed in order -> no barrier needed.
    bf16x8 pf0 = *(const bf16x8*)(&Plds[wave][lr][lq * 8]);
    bf16x8 pf1 = *(const bf16x8*)(&Plds[wave][16 + lr][lq * 8]);
    bf16x8 vf0 = *(const bf16x8*)(Vp + (size_t)lr * NPIX + kc + lq * 8);
    bf16x8 vf1 = *(const bf16x8*)(Vp + (size_t)(16 + lr) * NPIX + kc + lq * 8);
    O[0][0] = __builtin_amdgcn_mfma_f32_16x16x32_bf16(pf0, vf0, O[0][0], 0, 0, 0);
    O[0][1] = __builtin_amdgcn_mfma_f32_16x16x32_bf16(pf0, vf1, O[0][1], 0, 0, 0);
    O[1][0] = __builtin_amdgcn_mfma_f32_16x16x32_bf16(pf1, vf0, O[1][0], 0, 0, 0);
    O[1][1] = __builtin_amdgcn_mfma_f32_16x16x32_bf16(pf1, vf1, O[1][1], 0, 0, 0);
    Lf[0] = __builtin_amdgcn_mfma_f32_16x16x32_bf16(pf0, onef, Lf[0], 0, 0, 0);
    Lf[1] = __builtin_amdgcn_mfma_f32_16x16x32_bf16(pf1, onef, Lf[1], 0, 0, 0);
  }
  // epilogue: divide by row sum, store y[b, g*32+d, n] (bf16 ws)
#pragma unroll
  for (int qi = 0; qi < 2; ++qi) {
#pragma unroll
    for (int r = 0; r < 4; ++r) {
      int qrow = qbase + qi * 16 + lq * 4 + r;
      if (qrow < NPIX) {
        float inv = 1.0f / Lf[qi][r];
#pragma unroll
        for (int dh = 0; dh < 2; ++dh) {
          int d = dh * 16 + lr;
          y[((size_t)b * 128 + g * 32 + d) * NPIX + qrow] = f2b(O[qi][dh][r] * inv);
        }
      }
    }
  }
}

// ---------------------------------------------------------------------------
// Kernel 3: z = relu(bn(W_w @ y + W_b) + x)   (y bf16 ws, x fp32, z bf16 ws)
// ---------------------------------------------------------------------------
__global__ __launch_bounds__(256) void wz_kernel(
    const u16* __restrict__ y, const float* __restrict__ Ww, const float* __restrict__ Wb,
    const float* __restrict__ sc, const float* __restrict__ bi,
    const float* __restrict__ mu, const float* __restrict__ var,
    const float* __restrict__ x, u16* __restrict__ z) {
  __shared__ __align__(16) u16 sIn[128 * 64];
  __shared__ __align__(16) u16 sW[128 * 64];
  const int b = blockIdx.z, oc = blockIdx.y, nc = blockIdx.x;
  const int obase = oc * 64;
  float acc[4][4] = {};
  gemm_core<128, false>(y + (size_t)b * 128 * NPIX, nc * 64,
                        Ww + (size_t)obase * 128, acc, sIn, sW);
  const int to = (threadIdx.x >> 4) * 4;
  const int tn = (threadIdx.x & 15) * 4;
  const int n0 = nc * 64 + tn;
#pragma unroll
  for (int i = 0; i < 4; ++i) {
    int o = obase + to + i;
    float inv = sc[o] * rsqrtf(var[o] + 1e-5f);
    float off = bi[o] - mu[o] * inv;
    float wb = Wb[o];
    float4 xr = *(const float4*)(x + ((size_t)b * 256 + o) * NPIX + n0);
    float xv[4] = {xr.x, xr.y, xr.z, xr.w};
    float v[4];
#pragma unroll
    for (int j = 0; j < 4; ++j) v[j] = fmaxf((acc[i][j] + wb) * inv + off + xv[j], 0.f);
    uint2 s; s.x = pk2(v[0], v[1]); s.y = pk2(v[2], v[3]);
    *(uint2*)(z + ((size_t)b * 256 + o) * NPIX + n0) = s;
  }
}

// ---------------------------------------------------------------------------
// Kernel 4: o1 = relu(bn1(ff1_w @ z))   (z bf16 ws -> o1 bf16 ws)
// ---------------------------------------------------------------------------
__global__ __launch_bounds__(256) void ff1_kernel(
    const u16* __restrict__ z, const float* __restrict__ w,
    const float* __restrict__ sc, const float* __restrict__ bi,
    const float* __restrict__ mu, const float* __restrict__ var,
    u16* __restrict__ o1) {
  __shared__ __align__(16) u16 sIn[128 * 64];
  __shared__ __align__(16) u16 sW[128 * 64];
  const int b = blockIdx.z, nc = blockIdx.x;
  float acc[4][4] = {};
  gemm_core<256, false>(z + (size_t)b * 256 * NPIX, nc * 64, w, acc, sIn, sW);
  const int to = (threadIdx.x >> 4) * 4;
  const int tn = (threadIdx.x & 15) * 4;
  const int n0 = nc * 64 + tn;
#pragma unroll
  for (int i = 0; i < 4; ++i) {
    int o = to + i;
    float inv = sc[o] * rsqrtf(var[o] + 1e-5f);
    float off = bi[o] - mu[o] * inv;
    float v[4];
#pragma unroll
    for (int j = 0; j < 4; ++j) v[j] = fmaxf(acc[i][j] * inv + off, 0.f);
    uint2 s; s.x = pk2(v[0], v[1]); s.y = pk2(v[2], v[3]);
    *(uint2*)(o1 + ((size_t)b * 64 + o) * NPIX + n0) = s;
  }
}

// ---------------------------------------------------------------------------
// Kernel 5: o2 = relu(bn2(conv3x3_same(o1, ff2_w)))  (bf16 ws, fp32 weights)
// block: (b, co-chunk of 16, h-band of 4 rows); thread: (w-col, co-quad)
// Input channels in 2 chunks of 32: LDS ~ 24.6+9.2 KB (bf16 sI, bf16 sWt).
// ---------------------------------------------------------------------------
__global__ __launch_bounds__(256) void ff2_kernel(
    const u16* __restrict__ o1, const float* __restrict__ w,
    const float* __restrict__ sc, const float* __restrict__ bi,
    const float* __restrict__ mu, const float* __restrict__ var,
    u16* __restrict__ o2) {
  __shared__ __align__(16) u16 sI[32 * 6 * 64];    // [ci][r(6)][c(64)], halo, zero pad
  __shared__ __align__(16) u16 sWt[16 * 32 * 9];   // [co_local][ci][tap]
  const int b = blockIdx.z, cc = blockIdx.y, hb = blockIdx.x;
  const int h0 = hb * 4;
  const int tid = threadIdx.x;
  const int tw = tid & 63;
  const int tq = tid >> 6;
  const int twc = tw > 55 ? 55 : tw;   // keep LDS reads in-bounds for idle lanes
  float acc[4][4] = {};                // [co_j][h]
  for (int cch = 0; cch < 2; ++cch) {
    if (cch) __syncthreads();
    for (int i = tid; i < 32 * 6 * 64; i += 256) {
      int c = i & 63, r = (i >> 6) % 6, ci = i / 384;
      int gr = h0 - 1 + r, gc = c - 1;
      u16 v = 0;
      if (gr >= 0 && gr < 56 && gc >= 0 && gc < 56)
        v = o1[((size_t)b * 64 + cch * 32 + ci) * NPIX + gr * 56 + gc];
      sI[i] = v;
    }
    for (int i = tid; i < 16 * 32 * 9; i += 256) {
      int t = i % 9, ci = (i / 9) & 31, col = i / 288;
      sWt[i] = f2b(w[((size_t)(cc * 16 + col) * 64 + cch * 32 + ci) * 9 + t]);
    }
    __syncthreads();
    for (int ci = 0; ci < 32; ++ci) {
      float xv[6][3];
#pragma unroll
      for (int r = 0; r < 6; ++r)
#pragma unroll
        for (int dc = 0; dc < 3; ++dc)
          xv[r][dc] = b2f(sI[ci * 384 + r * 64 + twc + dc]);
#pragma unroll
      for (int cj = 0; cj < 4; ++cj) {
        int col = tq * 4 + cj;
        float wv[9];
#pragma unroll
        for (int t = 0; t < 9; ++t) wv[t] = b2f(sWt[col * 288 + ci * 9 + t]);
#pragma unroll
        for (int hh = 0; hh < 4; ++hh)
#pragma unroll
          for (int kh = 0; kh < 3; ++kh)
#pragma unroll
            for (int kw = 0; kw < 3; ++kw)
              acc[cj][hh] += wv[kh * 3 + kw] * xv[hh + kh][kw];
      }
    }
  }
  if (tw < 56) {
#pragma unroll
    for (int cj = 0; cj < 4; ++cj) {
      int co = cc * 16 + tq * 4 + cj;
      float inv = sc[co] * rsqrtf(var[co] + 1e-5f);
      float off = bi[co] - mu[co] * inv;
#pragma unroll
      for (int hh = 0; hh < 4; ++hh) {
        float v = fmaxf(acc[cj][hh] * inv + off, 0.f);
        o2[((size_t)b * 64 + co) * NPIX + (h0 + hh) * 56 + tw] = f2b(v);
      }
    }
  }
}

// ---------------------------------------------------------------------------
// Kernel 6: out = relu(bn3(ff3_w @ o2) + z)   (o2/z bf16 ws -> out fp32)
// ---------------------------------------------------------------------------
__global__ __launch_bounds__(256) void ff3_kernel(
    const u16* __restrict__ o2, const float* __restrict__ w,
    const float* __restrict__ sc, const float* __restrict__ bi,
    const float* __restrict__ mu, const float* __restrict__ var,
    const u16* __restrict__ z, float* __restrict__ out) {
  __shared__ __align__(16) u16 sIn[64 * 64];
  __shared__ __align__(16) u16 sW[64 * 64];
  const int b = blockIdx.z, oc = blockIdx.y, nc = blockIdx.x;
  const int obase = oc * 64;
  float acc[4][4] = {};
  gemm_core<64, false>(o2 + (size_t)b * 64 * NPIX, nc * 64,
                       w + (size_t)obase * 64, acc, sIn, sW);
  const int to = (threadIdx.x >> 4) * 4;
  const int tn = (threadIdx.x & 15) * 4;
  const int n0 = nc * 64 + tn;
#pragma unroll
  for (int i = 0; i < 4; ++i) {
    int o = obase + to + i;
    float inv = sc[o] * rsqrtf(var[o] + 1e-5f);
    float off = bi[o] - mu[o] * inv;
    uint2 zr = *(const uint2*)(z + ((size_t)b * 256 + o) * NPIX + n0);
    float zv[4];
    unpack4(zr.x, zr.y, zv);
    float4 s;
    s.x = fmaxf(acc[i][0] * inv + off + zv[0], 0.f);
    s.y = fmaxf(acc[i][1] * inv + off + zv[1], 0.f);
    s.z = fmaxf(acc[i][2] * inv + off + zv[2], 0.f);
    s.w = fmaxf(acc[i][3] * inv + off + zv[3], 0.f);
    *(float4*)(out + ((size_t)b * 256 + o) * NPIX + n0) = s;
  }
}

// ---------------------------------------------------------------------------
extern "C" void kernel_launch(void* const* d_in, const int* in_sizes, int n_in,
                              void* d_out, int out_size, void* d_ws, size_t ws_size,
                              hipStream_t stream) {
  const float* x    = (const float*)d_in[0];
  const float* gw   = (const float*)d_in[1];
  const float* gb   = (const float*)d_in[2];
  const float* tw   = (const float*)d_in[3];
  const float* tb   = (const float*)d_in[4];
  const float* pw   = (const float*)d_in[5];
  const float* pb   = (const float*)d_in[6];
  const float* Ww   = (const float*)d_in[7];
  const float* Wb   = (const float*)d_in[8];
  const float* bnWs = (const float*)d_in[9];
  const float* bnWb = (const float*)d_in[10];
  const float* bnWm = (const float*)d_in[11];
  const float* bnWv = (const float*)d_in[12];
  const float* f1w  = (const float*)d_in[13];
  const float* b1s  = (const float*)d_in[14];
  const float* b1b  = (const float*)d_in[15];
  const float* b1m  = (const float*)d_in[16];
  const float* b1v  = (const float*)d_in[17];
  const float* f2w  = (const float*)d_in[18];
  const float* b2s  = (const float*)d_in[19];
  const float* b2b  = (const float*)d_in[20];
  const float* b2m  = (const float*)d_in[21];
  const float* b2v  = (const float*)d_in[22];
  const float* f3w  = (const float*)d_in[23];
  const float* b3s  = (const float*)d_in[24];
  const float* b3b  = (const float*)d_in[25];
  const float* b3m  = (const float*)d_in[26];
  const float* b3v  = (const float*)d_in[27];
  float* out = (float*)d_out;

  const size_t SLAB = (size_t)BB * 128 * NPIX;   // 1,605,632 bf16 elements
  u16* Tq  = (u16*)d_ws;
  u16* Pk  = Tq + SLAB;
  u16* gxv = Pk + SLAB;
  u16* yv  = gxv + SLAB;
  u16* zv  = yv + SLAB;          // 2*SLAB elements (B,256,N)
  u16* o1v = zv + 2 * SLAB;      // SLAB/2
  u16* o2v = o1v + SLAB / 2;     // SLAB/2  (total 7*SLAB = 22.5 MB)

  proj_kernel<<<dim3(49, 6, BB), 256, 0, stream>>>(x, gw, gb, tw, tb, pw, pb, gxv, Tq, Pk);
  attn_kernel<<<dim3(16 * 25), 256, 0, stream>>>(Tq, Pk, gxv, yv);
  wz_kernel<<<dim3(49, 4, BB), 256, 0, stream>>>(yv, Ww, Wb, bnWs, bnWb, bnWm, bnWv, x, zv);
  ff1_kernel<<<dim3(49, 1, BB), 256, 0, stream>>>(zv, f1w, b1s, b1b, b1m, b1v, o1v);
  ff2_kernel<<<dim3(14, 4, BB), 256, 0, stream>>>(o1v, f2w, b2s, b2b, b2m, b2v, o2v);
  ff3_kernel<<<dim3(49, 4, BB), 256, 0, stream>>>(o2v, f3w, b3s, b3b, b3m, b3v, zv, out);
}

// Round 5
// 262.259 us; speedup vs baseline: 1.5716x; 1.5716x over previous
//
#include <hip/hip_runtime.h>
#include <hip/hip_bf16.h>

#define NPIX 3136
#define BB 4

typedef unsigned short u16;
typedef __bf16 bf16x8 __attribute__((ext_vector_type(8)));
typedef float f32x4 __attribute__((ext_vector_type(4)));

__device__ __forceinline__ float b2f(u16 u) {
  union { unsigned u; float f; } c; c.u = ((unsigned)u) << 16; return c.f;
}
__device__ __forceinline__ u16 f2b(float f) {
  __hip_bfloat16 h = __float2bfloat16(f);
  return *reinterpret_cast<u16*>(&h);
}
__device__ __forceinline__ unsigned pk2(float a, float b) {
  return (unsigned)f2b(a) | ((unsigned)f2b(b) << 16);
}

// ---------------------------------------------------------------------------
// Shared MFMA wave-GEMM: one wave computes a 16n x 64o tile over K=NSTEP*32.
// Arow: A-row base for THIS lane (lane's n-row applied), stride strideA (u16).
// Brow: B-row base for lane's lr (o-row lr applied), stride strideB (u16).
// Validated orientation (R4 attention): D row = A row (n), D col = B row (o);
// epilogue: value acc[ot][r] -> n = ntile + lq*4 + r, o = ot*16 + lr.
// ---------------------------------------------------------------------------
template<int NSTEP>
__device__ __forceinline__ void mf_gemm(const u16* __restrict__ Arow, int strideA,
                                        const u16* __restrict__ Brow, int strideB,
                                        int lq, f32x4 acc[4]) {
#pragma unroll
  for (int s = 0; s < NSTEP; ++s) {
    bf16x8 af = *(const bf16x8*)(Arow + s * 32 + lq * 8);
#pragma unroll
    for (int ot = 0; ot < 4; ++ot) {
      bf16x8 bf = *(const bf16x8*)(Brow + (size_t)ot * 16 * strideB + s * 32 + lq * 8);
      acc[ot] = __builtin_amdgcn_mfma_f32_16x16x32_bf16(af, bf, acc[ot], 0, 0, 0);
    }
  }
}

// ---------------------------------------------------------------------------
// prep_w: convert all weights to bf16 (f2w repacked tap-major [t][co][ci]).
// ---------------------------------------------------------------------------
__global__ __launch_bounds__(256) void prep_w(
    const float* __restrict__ gw, const float* __restrict__ tw,
    const float* __restrict__ pw, const float* __restrict__ Ww,
    const float* __restrict__ f1w, const float* __restrict__ f2w,
    const float* __restrict__ f3w,
    u16* __restrict__ gwb, u16* __restrict__ twb, u16* __restrict__ pwb,
    u16* __restrict__ Wwb, u16* __restrict__ f1b, u16* __restrict__ f3b,
    u16* __restrict__ f2p) {
  for (int i = blockIdx.x * 256 + threadIdx.x; i < 200704; i += gridDim.x * 256) {
    int j = i;
    if (j < 32768) { gwb[j] = f2b(gw[j]); continue; } j -= 32768;
    if (j < 32768) { twb[j] = f2b(tw[j]); continue; } j -= 32768;
    if (j < 32768) { pwb[j] = f2b(pw[j]); continue; } j -= 32768;
    if (j < 32768) { Wwb[j] = f2b(Ww[j]); continue; } j -= 32768;
    if (j < 16384) { f1b[j] = f2b(f1w[j]); continue; } j -= 16384;
    if (j < 16384) { f3b[j] = f2b(f3w[j]); continue; } j -= 16384;
    int t = j >> 12, rem = j & 4095, co = rem >> 6, ci = rem & 63;
    f2p[j] = f2b(f2w[(co * 64 + ci) * 9 + t]);
  }
}

// ---------------------------------------------------------------------------
// prep_x: xt[b][n][c] = bf16(x[b][c][n]) via 64x64 LDS tile transpose.
// ---------------------------------------------------------------------------
__global__ __launch_bounds__(256) void prep_x(const float* __restrict__ x,
                                              u16* __restrict__ xt) {
  __shared__ u16 sT[64 * 65];
  const int b = blockIdx.z, c0 = blockIdx.y * 64, n0 = blockIdx.x * 64;
  const int t = threadIdx.x;
#pragma unroll
  for (int cc = 0; cc < 4; ++cc) {
    int c = cc * 16 + (t >> 4), n4 = (t & 15) * 4;
    float4 v = *(const float4*)(x + ((size_t)(b * 256 + c0 + c)) * NPIX + n0 + n4);
    sT[c * 65 + n4 + 0] = f2b(v.x);
    sT[c * 65 + n4 + 1] = f2b(v.y);
    sT[c * 65 + n4 + 2] = f2b(v.z);
    sT[c * 65 + n4 + 3] = f2b(v.w);
  }
  __syncthreads();
#pragma unroll
  for (int nn = 0; nn < 4; ++nn) {
    int n = nn * 16 + (t >> 4), c4 = (t & 15) * 4;
    uint2 s;
    s.x = (unsigned)sT[(c4 + 0) * 65 + n] | ((unsigned)sT[(c4 + 1) * 65 + n] << 16);
    s.y = (unsigned)sT[(c4 + 2) * 65 + n] | ((unsigned)sT[(c4 + 3) * 65 + n] << 16);
    *(uint2*)(xt + ((size_t)b * NPIX + n0 + n) * 256 + c0 + c4) = s;
  }
}

// ---------------------------------------------------------------------------
// proj: MFMA. Out^T(n,o) = xt(n,256) . W^T. oc section: 0,1=g 2,3=theta 4,5=phi
// ---------------------------------------------------------------------------
__global__ __launch_bounds__(256) void proj_kernel(
    const u16* __restrict__ xt,
    const u16* __restrict__ gwb, const u16* __restrict__ twb, const u16* __restrict__ pwb,
    const float* __restrict__ gb, const float* __restrict__ tb, const float* __restrict__ pb,
    u16* __restrict__ gx, u16* __restrict__ Tq, u16* __restrict__ Pk) {
  const int b = blockIdx.z, oc = blockIdx.y, nb = blockIdx.x * 64;
  const int sec = oc >> 1, rbase = (oc & 1) * 64;
  const u16* wsel = sec == 0 ? gwb : (sec == 1 ? twb : pwb);
  const float* bsel = sec == 0 ? gb : (sec == 1 ? tb : pb);
  const int wv = threadIdx.x >> 6, lane = threadIdx.x & 63;
  const int lr = lane & 15, lq = lane >> 4;
  const int nrow = nb + wv * 16;
  f32x4 acc[4] = {};
  mf_gemm<8>(xt + ((size_t)b * NPIX + nrow + lr) * 256, 256,
             wsel + (size_t)(rbase + lr) * 256, 256, lq, acc);
#pragma unroll
  for (int ot = 0; ot < 4; ++ot) {
    const int o = rbase + ot * 16 + lr;      // 0..127 within section
    const float bias = bsel[o];
    if (sec == 0) {
#pragma unroll
      for (int r = 0; r < 4; ++r)
        gx[((size_t)b * 128 + o) * NPIX + nrow + lq * 4 + r] = f2b(acc[ot][r] + bias);
    } else {
      const int g = o >> 5, dl = o & 31;
      u16* dst = sec == 1 ? Tq : Pk;
      size_t base = (size_t)(b * 4 + g) * NPIX;
#pragma unroll
      for (int r = 0; r < 4; ++r)
        dst[(base + nrow + lq * 4 + r) * 32 + dl] = f2b(acc[ot][r] + bias);
    }
  }
}

// ---------------------------------------------------------------------------
// attn: split-K x4 flash attention. Chunks 800/800/800/736 keys (all %32==0).
// Un-normalized partials: OP fp32 (ks,bg,n,32), LP fp32 (ks,bg,n).
// ---------------------------------------------------------------------------
__global__ __launch_bounds__(256) void attn_kernel(
    const u16* __restrict__ Tq, const u16* __restrict__ Pk,
    const u16* __restrict__ gx, float* __restrict__ OP, float* __restrict__ LP) {
  __shared__ __align__(16) u16 Plds[4][32][40];
  const int bid = blockIdx.x;
  const int ks = bid / 400, rem = bid % 400;
  const int bg = rem / 25, qblk = rem % 25;
  const int b = bg >> 2, g = bg & 3;
  const int wave = threadIdx.x >> 6, lane = threadIdx.x & 63;
  const int lr = lane & 15, lq = lane >> 4;
  const int qbase = qblk * 128 + wave * 32;
  const int kc0 = ks * 800;
  const int kc1 = (kc0 + 800 < NPIX) ? kc0 + 800 : NPIX;
  const u16* Qp = Tq + (size_t)bg * NPIX * 32;
  const u16* Kp = Pk + (size_t)bg * NPIX * 32;
  const u16* Vp = gx + ((size_t)b * 128 + g * 32) * NPIX;

  bf16x8 qf[2];
#pragma unroll
  for (int qi = 0; qi < 2; ++qi) {
    int row = qbase + qi * 16 + lr;
    row = row < NPIX ? row : NPIX - 1;
    qf[qi] = *(const bf16x8*)(Qp + (size_t)row * 32 + lq * 8);
  }
  const f32x4 z4 = {0.f, 0.f, 0.f, 0.f};
  f32x4 O[2][2], Lf[2];
#pragma unroll
  for (int qi = 0; qi < 2; ++qi) { O[qi][0] = z4; O[qi][1] = z4; Lf[qi] = z4; }
  bf16x8 onef;
#pragma unroll
  for (int j = 0; j < 8; ++j) onef[j] = (__bf16)1.0f;

  for (int kc = kc0; kc < kc1; kc += 32) {
    bf16x8 kf0 = *(const bf16x8*)(Kp + (size_t)(kc + lr) * 32 + lq * 8);
    bf16x8 kf1 = *(const bf16x8*)(Kp + (size_t)(kc + 16 + lr) * 32 + lq * 8);
    f32x4 S[2][2];
    S[0][0] = __builtin_amdgcn_mfma_f32_16x16x32_bf16(qf[0], kf0, z4, 0, 0, 0);
    S[0][1] = __builtin_amdgcn_mfma_f32_16x16x32_bf16(qf[0], kf1, z4, 0, 0, 0);
    S[1][0] = __builtin_amdgcn_mfma_f32_16x16x32_bf16(qf[1], kf0, z4, 0, 0, 0);
    S[1][1] = __builtin_amdgcn_mfma_f32_16x16x32_bf16(qf[1], kf1, z4, 0, 0, 0);
#pragma unroll
    for (int qi = 0; qi < 2; ++qi)
#pragma unroll
      for (int kt = 0; kt < 2; ++kt)
#pragma unroll
        for (int r = 0; r < 4; ++r) {
          float p = __expf(fminf(S[qi][kt][r], 60.f));
          Plds[wave][qi * 16 + lq * 4 + r][kt * 16 + lr] = f2b(p);
        }
    bf16x8 pf0 = *(const bf16x8*)(&Plds[wave][lr][lq * 8]);
    bf16x8 pf1 = *(const bf16x8*)(&Plds[wave][16 + lr][lq * 8]);
    bf16x8 vf0 = *(const bf16x8*)(Vp + (size_t)lr * NPIX + kc + lq * 8);
    bf16x8 vf1 = *(const bf16x8*)(Vp + (size_t)(16 + lr) * NPIX + kc + lq * 8);
    O[0][0] = __builtin_amdgcn_mfma_f32_16x16x32_bf16(pf0, vf0, O[0][0], 0, 0, 0);
    O[0][1] = __builtin_amdgcn_mfma_f32_16x16x32_bf16(pf0, vf1, O[0][1], 0, 0, 0);
    O[1][0] = __builtin_amdgcn_mfma_f32_16x16x32_bf16(pf1, vf0, O[1][0], 0, 0, 0);
    O[1][1] = __builtin_amdgcn_mfma_f32_16x16x32_bf16(pf1, vf1, O[1][1], 0, 0, 0);
    Lf[0] = __builtin_amdgcn_mfma_f32_16x16x32_bf16(pf0, onef, Lf[0], 0, 0, 0);
    Lf[1] = __builtin_amdgcn_mfma_f32_16x16x32_bf16(pf1, onef, Lf[1], 0, 0, 0);
  }
  const size_t sbase = (size_t)(ks * 16 + bg) * NPIX;
#pragma unroll
  for (int qi = 0; qi < 2; ++qi) {
#pragma unroll
    for (int r = 0; r < 4; ++r) {
      int qrow = qbase + qi * 16 + lq * 4 + r;
      if (qrow < NPIX) {
        size_t ob = (sbase + qrow) * 32;
        OP[ob + lr] = O[qi][0][r];
        OP[ob + 16 + lr] = O[qi][1][r];
        if (lr == 0) LP[sbase + qrow] = Lf[qi][r];
      }
    }
  }
}

// ---------------------------------------------------------------------------
// combine: yt[b][n][g*32+d] = sum_ks OP / sum_ks LP
// ---------------------------------------------------------------------------
__global__ __launch_bounds__(256) void combine_kernel(
    const float* __restrict__ OP, const float* __restrict__ LP,
    u16* __restrict__ yt) {
  const int bg = blockIdx.y, b = bg >> 2, g = bg & 3;
  const int t = threadIdx.x;
  const int n = blockIdx.x * 64 + (t >> 2);
  const int dseg = (t & 3) * 8;
  float4 a0 = {0, 0, 0, 0}, a1 = {0, 0, 0, 0};
  float l = 0.f;
#pragma unroll
  for (int ks = 0; ks < 4; ++ks) {
    size_t base = ((size_t)(ks * 16 + bg) * NPIX + n) * 32 + dseg;
    float4 v0 = *(const float4*)(OP + base);
    float4 v1 = *(const float4*)(OP + base + 4);
    a0.x += v0.x; a0.y += v0.y; a0.z += v0.z; a0.w += v0.w;
    a1.x += v1.x; a1.y += v1.y; a1.z += v1.z; a1.w += v1.w;
    l += LP[(size_t)(ks * 16 + bg) * NPIX + n];
  }
  float inv = 1.0f / l;
  uint4 s;
  s.x = pk2(a0.x * inv, a0.y * inv);
  s.y = pk2(a0.z * inv, a0.w * inv);
  s.z = pk2(a1.x * inv, a1.y * inv);
  s.w = pk2(a1.z * inv, a1.w * inv);
  *(uint4*)(yt + ((size_t)b * NPIX + n) * 128 + g * 32 + dseg) = s;
}

// ---------------------------------------------------------------------------
// wz: zt(n,256) = relu(bn(Ww . y + Wb) + x)
// ---------------------------------------------------------------------------
__global__ __launch_bounds__(256) void wz_kernel(
    const u16* __restrict__ yt, const u16* __restrict__ Wwb, const float* __restrict__ Wb,
    const float* __restrict__ sc, const float* __restrict__ bi,
    const float* __restrict__ mu, const float* __restrict__ var,
    const float* __restrict__ x, u16* __restrict__ zt) {
  const int b = blockIdx.z, oc = blockIdx.y, nb = blockIdx.x * 64;
  const int wv = threadIdx.x >> 6, lane = threadIdx.x & 63;
  const int lr = lane & 15, lq = lane >> 4;
  const int nrow = nb + wv * 16;
  f32x4 acc[4] = {};
  mf_gemm<4>(yt + ((size_t)b * NPIX + nrow + lr) * 128, 128,
             Wwb + (size_t)(oc * 64 + lr) * 128, 128, lq, acc);
#pragma unroll
  for (int ot = 0; ot < 4; ++ot) {
    const int o = oc * 64 + ot * 16 + lr;
    float inv = sc[o] * rsqrtf(var[o] + 1e-5f);
    float off = bi[o] - mu[o] * inv + Wb[o] * inv;
    float4 xr = *(const float4*)(x + ((size_t)b * 256 + o) * NPIX + nrow + lq * 4);
    float xv[4] = {xr.x, xr.y, xr.z, xr.w};
#pragma unroll
    for (int r = 0; r < 4; ++r) {
      float v = fmaxf(acc[ot][r] * inv + off + xv[r], 0.f);
      zt[((size_t)b * NPIX + nrow + lq * 4 + r) * 256 + o] = f2b(v);
    }
  }
}

// ---------------------------------------------------------------------------
// ff1: o1t(n,64) = relu(bn1(f1 . z))
// ---------------------------------------------------------------------------
__global__ __launch_bounds__(256) void ff1_kernel(
    const u16* __restrict__ zt, const u16* __restrict__ f1b,
    const float* __restrict__ sc, const float* __restrict__ bi,
    const float* __restrict__ mu, const float* __restrict__ var,
    u16* __restrict__ o1t) {
  const int b = blockIdx.z, nb = blockIdx.x * 64;
  const int wv = threadIdx.x >> 6, lane = threadIdx.x & 63;
  const int lr = lane & 15, lq = lane >> 4;
  const int nrow = nb + wv * 16;
  f32x4 acc[4] = {};
  mf_gemm<8>(zt + ((size_t)b * NPIX + nrow + lr) * 256, 256,
             f1b + (size_t)lr * 256, 256, lq, acc);
#pragma unroll
  for (int ot = 0; ot < 4; ++ot) {
    const int o = ot * 16 + lr;
    float inv = sc[o] * rsqrtf(var[o] + 1e-5f);
    float off = bi[o] - mu[o] * inv;
#pragma unroll
    for (int r = 0; r < 4; ++r) {
      float v = fmaxf(acc[ot][r] * inv + off, 0.f);
      o1t[((size_t)b * NPIX + nrow + lq * 4 + r) * 64 + o] = f2b(v);
    }
  }
}

// ---------------------------------------------------------------------------
// ff2: o2t(n,64) = relu(bn2(conv3x3(o1))) as im2col MFMA.
// Per-lane A-row predication handles image boundaries (zero A row).
// ---------------------------------------------------------------------------
__global__ __launch_bounds__(256) void ff2_kernel(
    const u16* __restrict__ o1t, const u16* __restrict__ f2p,
    const float* __restrict__ sc, const float* __restrict__ bi,
    const float* __restrict__ mu, const float* __restrict__ var,
    u16* __restrict__ o2t) {
  const int b = blockIdx.z, nb = blockIdx.x * 64;
  const int wv = threadIdx.x >> 6, lane = threadIdx.x & 63;
  const int lr = lane & 15, lq = lane >> 4;
  const int n_row = nb + wv * 16 + lr;         // A-row pixel for this lane
  const int h = n_row / 56, w = n_row % 56;
  f32x4 acc[4] = {};
#pragma unroll
  for (int t = 0; t < 9; ++t) {
    const int dh = t / 3 - 1, dw = t % 3 - 1;
    const bool valid = (h + dh) >= 0 && (h + dh) < 56 && (w + dw) >= 0 && (w + dw) < 56;
    const u16* Ar = o1t + ((size_t)b * NPIX + n_row + dh * 56 + dw) * 64;
    const u16* Br = f2p + ((size_t)t * 64 + lr) * 64;
#pragma unroll
    for (int k2 = 0; k2 < 2; ++k2) {
      bf16x8 af = {};
      if (valid) af = *(const bf16x8*)(Ar + k2 * 32 + lq * 8);
#pragma unroll
      for (int ot = 0; ot < 4; ++ot) {
        bf16x8 bf = *(const bf16x8*)(Br + (size_t)ot * 16 * 64 + k2 * 32 + lq * 8);
        acc[ot] = __builtin_amdgcn_mfma_f32_16x16x32_bf16(af, bf, acc[ot], 0, 0, 0);
      }
    }
  }
  const int nrow = nb + wv * 16;
#pragma unroll
  for (int ot = 0; ot < 4; ++ot) {
    const int o = ot * 16 + lr;
    float inv = sc[o] * rsqrtf(var[o] + 1e-5f);
    float off = bi[o] - mu[o] * inv;
#pragma unroll
    for (int r = 0; r < 4; ++r) {
      float v = fmaxf(acc[ot][r] * inv + off, 0.f);
      o2t[((size_t)b * NPIX + nrow + lq * 4 + r) * 64 + o] = f2b(v);
    }
  }
}

// ---------------------------------------------------------------------------
// ff3: out(b,256,N) fp32 = relu(bn3(f3 . o2) + z)
// ---------------------------------------------------------------------------
__global__ __launch_bounds__(256) void ff3_kernel(
    const u16* __restrict__ o2t, const u16* __restrict__ f3b,
    const float* __restrict__ sc, const float* __restrict__ bi,
    const float* __restrict__ mu, const float* __restrict__ var,
    const u16* __restrict__ zt, float* __restrict__ out) {
  const int b = blockIdx.z, oc = blockIdx.y, nb = blockIdx.x * 64;
  const int wv = threadIdx.x >> 6, lane = threadIdx.x & 63;
  const int lr = lane & 15, lq = lane >> 4;
  const int nrow = nb + wv * 16;
  f32x4 acc[4] = {};
  mf_gemm<2>(o2t + ((size_t)b * NPIX + nrow + lr) * 64, 64,
             f3b + (size_t)(oc * 64 + lr) * 64, 64, lq, acc);
#pragma unroll
  for (int ot = 0; ot < 4; ++ot) {
    const int o = oc * 64 + ot * 16 + lr;
    float inv = sc[o] * rsqrtf(var[o] + 1e-5f);
    float off = bi[o] - mu[o] * inv;
    float4 s;
    float* sv = (float*)&s;
#pragma unroll
    for (int r = 0; r < 4; ++r) {
      float zres = b2f(zt[((size_t)b * NPIX + nrow + lq * 4 + r) * 256 + o]);
      sv[r] = fmaxf(acc[ot][r] * inv + off + zres, 0.f);
    }
    *(float4*)(out + ((size_t)b * 256 + o) * NPIX + nrow + lq * 4) = s;
  }
}

// ---------------------------------------------------------------------------
extern "C" void kernel_launch(void* const* d_in, const int* in_sizes, int n_in,
                              void* d_out, int out_size, void* d_ws, size_t ws_size,
                              hipStream_t stream) {
  const float* x    = (const float*)d_in[0];
  const float* gw   = (const float*)d_in[1];
  const float* gb   = (const float*)d_in[2];
  const float* tw   = (const float*)d_in[3];
  const float* tb   = (const float*)d_in[4];
  const float* pw   = (const float*)d_in[5];
  const float* pb   = (const float*)d_in[6];
  const float* Ww   = (const float*)d_in[7];
  const float* Wb   = (const float*)d_in[8];
  const float* bnWs = (const float*)d_in[9];
  const float* bnWb = (const float*)d_in[10];
  const float* bnWm = (const float*)d_in[11];
  const float* bnWv = (const float*)d_in[12];
  const float* f1w  = (const float*)d_in[13];
  const float* b1s  = (const float*)d_in[14];
  const float* b1b  = (const float*)d_in[15];
  const float* b1m  = (const float*)d_in[16];
  const float* b1v  = (const float*)d_in[17];
  const float* f2w  = (const float*)d_in[18];
  const float* b2s  = (const float*)d_in[19];
  const float* b2b  = (const float*)d_in[20];
  const float* b2m  = (const float*)d_in[21];
  const float* b2v  = (const float*)d_in[22];
  const float* f3w  = (const float*)d_in[23];
  const float* b3s  = (const float*)d_in[24];
  const float* b3b  = (const float*)d_in[25];
  const float* b3m  = (const float*)d_in[26];
  const float* b3v  = (const float*)d_in[27];
  float* out = (float*)d_out;

  u16* p = (u16*)d_ws;
  u16* xt  = p; p += (size_t)BB * NPIX * 256;      // 3,211,264
  u16* gwb = p; p += 128 * 256;
  u16* twb = p; p += 128 * 256;
  u16* pwb = p; p += 128 * 256;
  u16* Wwb = p; p += 256 * 128;
  u16* f1b = p; p += 64 * 256;
  u16* f3b = p; p += 256 * 64;
  u16* f2p = p; p += 9 * 64 * 64;
  u16* Tq  = p; p += (size_t)16 * NPIX * 32;
  u16* Pk  = p; p += (size_t)16 * NPIX * 32;
  u16* gx  = p; p += (size_t)BB * 128 * NPIX;
  u16* yt  = p; p += (size_t)BB * NPIX * 128;
  float* OP = (float*)p;                           // 4 ks x 16 bg x N x 32
  float* LP = OP + (size_t)4 * 16 * NPIX * 32;
  // OP region is dead after combine; reuse for zt/o1t/o2t (9.6MB < 25.7MB):
  u16* zt  = (u16*)OP;
  u16* o1t = zt + (size_t)BB * NPIX * 256;
  u16* o2t = o1t + (size_t)BB * NPIX * 64;

  prep_w<<<dim3(196), 256, 0, stream>>>(gw, tw, pw, Ww, f1w, f2w, f3w,
                                        gwb, twb, pwb, Wwb, f1b, f3b, f2p);
  prep_x<<<dim3(49, 4, BB), 256, 0, stream>>>(x, xt);
  proj_kernel<<<dim3(49, 6, BB), 256, 0, stream>>>(xt, gwb, twb, pwb, gb, tb, pb,
                                                   gx, Tq, Pk);
  attn_kernel<<<dim3(1600), 256, 0, stream>>>(Tq, Pk, gx, OP, LP);
  combine_kernel<<<dim3(49, 16), 256, 0, stream>>>(OP, LP, yt);
  wz_kernel<<<dim3(49, 4, BB), 256, 0, stream>>>(yt, Wwb, Wb, bnWs, bnWb, bnWm, bnWv,
                                                 x, zt);
  ff1_kernel<<<dim3(49, 1, BB), 256, 0, stream>>>(zt, f1b, b1s, b1b, b1m, b1v, o1t);
  ff2_kernel<<<dim3(49, 1, BB), 256, 0, stream>>>(o1t, f2p, b2s, b2b, b2m, b2v, o2t);
  ff3_kernel<<<dim3(49, 4, BB), 256, 0, stream>>>(o2t, f3b, b3s, b3b, b3m, b3v, zt, out);
}